// Round 9
// baseline (1059.201 us; speedup 1.0000x reference)
//
#include <hip/hip_runtime.h>
#include <hip/hip_bf16.h>
#include <math.h>

#define B     8
#define S     512
#define MEM   512
#define L     4
#define E     512
#define H     8
#define DH    64
#define OBS   128
#define KLEN  1024   // MEM + S
#define FQ    64     // flash: q rows per block
#define FK    64     // flash: k per tile

typedef __hip_bfloat16 bf16;
using frag_ab = __attribute__((ext_vector_type(8))) short;   // 8 bf16 (4 VGPRs)
using frag_cd = __attribute__((ext_vector_type(4))) float;   // 4 fp32 acc

__device__ __forceinline__ float gelu_tanh(float x) {
    return 0.5f * x * (1.0f + tanhf(0.7978845608028654f * (x + 0.044715f * x * x * x)));
}
__device__ __forceinline__ unsigned short f2bs(float x) {
    bf16 h = __float2bfloat16(x); return *(unsigned short*)&h;
}
__device__ __forceinline__ float bs2f(short s) {
    union { unsigned u; float f; } t; t.u = ((unsigned)(unsigned short)s) << 16; return t.f;
}

// ---------------- merged setup: obs cast + positional embedding --------------
__global__ __launch_bounds__(256) void setup_kernel(
    const float* __restrict__ obs, bf16* __restrict__ obsb, bf16* __restrict__ pe)
{
    const int i = blockIdx.x * 256 + threadIdx.x;
    if (i < B * S * OBS) {
        obsb[i] = __float2bfloat16(obs[i]);
    } else {
        const int idx = i - B * S * OBS;
        const int p = idx >> 9;
        const int j = idx & 511;
        const float pos = (float)(KLEN - p);
        const int m = (j < 256) ? j : (j - 256);
        const float invf = expf(-(float)(2 * m) * (9.210340371976184f / (float)E));
        const float a = pos * invf;
        pe[idx] = __float2bfloat16((j < 256) ? sinf(a) : cosf(a));
    }
}

// ------- merged weight transposes: z = which*4 + li; z==28 -> Wenc -----------
__global__ __launch_bounds__(256) void transpose_all_kernel(
    const float* __restrict__ Wq, const float* __restrict__ Wk,
    const float* __restrict__ Wv, const float* __restrict__ Wr,
    const float* __restrict__ Wo, const float* __restrict__ W1,
    const float* __restrict__ W2, const float* __restrict__ Wenc,
    bf16* __restrict__ WqT, bf16* __restrict__ WkvT, bf16* __restrict__ WrT,
    bf16* __restrict__ WoT, bf16* __restrict__ W1T, bf16* __restrict__ W2T,
    bf16* __restrict__ WencT)
{
    __shared__ float t[32][33];
    const int z = blockIdx.z;
    const int bn = blockIdx.x * 32, bk = blockIdx.y * 32;
    const int tx = threadIdx.x & 31, ty = threadIdx.x >> 5;
    if (z == 28) {                         // Wenc: [OBS][E] -> [E][OBS]
        if (blockIdx.y >= OBS / 32) return;
        #pragma unroll
        for (int r = 0; r < 32; r += 8)
            t[ty + r][tx] = Wenc[(size_t)(bk + ty + r) * E + bn + tx];
        __syncthreads();
        #pragma unroll
        for (int r = 0; r < 32; r += 8)
            WencT[(size_t)(bn + ty + r) * OBS + bk + tx] = __float2bfloat16(t[tx][ty + r]);
        return;
    }
    const int which = z >> 2, li = z & 3;
    const size_t so = (size_t)li * E * E;
    const float* src; bf16* dst;
    switch (which) {
        case 0: src = Wq + so; dst = WqT + so; break;
        case 1: src = Wk + so; dst = WkvT + (size_t)li * 2 * E * E; break;
        case 2: src = Wv + so; dst = WkvT + (size_t)li * 2 * E * E + (size_t)E * E; break;
        case 3: src = Wr + so; dst = WrT + so; break;
        case 4: src = Wo + so; dst = WoT + so; break;
        case 5: src = W1 + so; dst = W1T + so; break;
        default: src = W2 + so; dst = W2T + so; break;
    }
    #pragma unroll
    for (int r = 0; r < 32; r += 8)
        t[ty + r][tx] = src[(size_t)(bk + ty + r) * E + bn + tx];
    __syncthreads();
    #pragma unroll
    for (int r = 0; r < 32; r += 8)
        dst[(size_t)(bn + ty + r) * E + bk + tx] = __float2bfloat16(t[tx][ty + r]);
}

// ---------------- V transpose: Vn[B*KLEN][E] bf16 -> Vt[B][E][KLEN] bf16 -----
__global__ __launch_bounds__(256) void transpose_v_kernel(
    const bf16* __restrict__ Vn, bf16* __restrict__ Vt)
{
    __shared__ short ts[64][72];
    const int k0 = blockIdx.x * 64, d0 = blockIdx.y * 64, b = blockIdx.z;
    const int t = threadIdx.x;
    const int r = t >> 2, c = (t & 3) * 16;
    const short* src = (const short*)Vn + ((size_t)(b * KLEN + k0 + r)) * E + d0 + c;
    *(uint4*)&ts[r][c]     = *(const uint4*)(src);
    *(uint4*)&ts[r][c + 8] = *(const uint4*)(src + 8);
    __syncthreads();
    short vals[16];
    #pragma unroll
    for (int i = 0; i < 16; ++i) vals[i] = ts[c + i][r];
    short* dst = (short*)Vt + ((size_t)(b * E + d0 + r)) * KLEN + k0 + c;
    *(uint4*)(dst)     = *(const uint4*)&vals[0];
    *(uint4*)(dst + 8) = *(const uint4*)&vals[8];
}

// ---------------- GEMM tile body: 128m x 64n, BK=64, 4 waves of 64x32 --------
__device__ __forceinline__ void gemm_body(
    short* As, short* Bs,
    const bf16* __restrict__ A, const bf16* __restrict__ Bt,
    int m0, int n0, int K, int N,
    const float* bias, const float* bias_u, const float* bias_v,
    const float* res, float* Cf, bf16* Cb, bf16* Cb2, int act, int mode)
{
    const int tid = threadIdx.x;
    const int w = tid >> 6, lane = tid & 63;
    const int wm2 = (w >> 1) * 64, wn2 = (w & 1) * 32;
    const int fr = lane & 15, quad = lane >> 4;

    const int arow = tid >> 1, acol = (tid & 1) * 32;
    const int brow = tid >> 2, bcol = (tid & 3) * 16;
    const short* Ag = (const short*)A + (size_t)(m0 + arow) * K + acol;
    const short* Bg = (const short*)Bt + (size_t)(n0 + brow) * K + bcol;
    short* Asw = &As[arow * 72 + acol];
    short* Bsw = &Bs[brow * 72 + bcol];

    frag_cd acc[4][2];
    #pragma unroll
    for (int i = 0; i < 4; ++i)
        #pragma unroll
        for (int j = 0; j < 2; ++j)
            acc[i][j] = (frag_cd)(0.0f);

    for (int k0 = 0; k0 < K; k0 += 64) {
        const uint4 a0 = *(const uint4*)(Ag + k0);
        const uint4 a1 = *(const uint4*)(Ag + k0 + 8);
        const uint4 a2 = *(const uint4*)(Ag + k0 + 16);
        const uint4 a3 = *(const uint4*)(Ag + k0 + 24);
        const uint4 b0 = *(const uint4*)(Bg + k0);
        const uint4 b1 = *(const uint4*)(Bg + k0 + 8);
        __syncthreads();
        *(uint4*)(Asw) = a0; *(uint4*)(Asw + 8) = a1;
        *(uint4*)(Asw + 16) = a2; *(uint4*)(Asw + 24) = a3;
        *(uint4*)(Bsw) = b0; *(uint4*)(Bsw + 8) = b1;
        __syncthreads();
        #pragma unroll
        for (int kh = 0; kh < 2; ++kh) {
            frag_ab af[4], bfr[2];
            #pragma unroll
            for (int i = 0; i < 4; ++i)
                af[i] = *(const frag_ab*)&As[(wm2 + i * 16 + fr) * 72 + kh * 32 + quad * 8];
            #pragma unroll
            for (int j = 0; j < 2; ++j)
                bfr[j] = *(const frag_ab*)&Bs[(wn2 + j * 16 + fr) * 72 + kh * 32 + quad * 8];
            #pragma unroll
            for (int i = 0; i < 4; ++i)
                #pragma unroll
                for (int j = 0; j < 2; ++j)
                    acc[i][j] = __builtin_amdgcn_mfma_f32_16x16x32_bf16(af[i], bfr[j], acc[i][j], 0, 0, 0);
        }
    }

    #pragma unroll
    for (int i = 0; i < 4; ++i) {
        #pragma unroll
        for (int r = 0; r < 4; ++r) {
            const int m = m0 + wm2 + i * 16 + quad * 4 + r;
            #pragma unroll
            for (int j = 0; j < 2; ++j) {
                const int n = n0 + wn2 + j * 16 + fr;
                float v = acc[i][j][r];
                if (bias) v += bias[n];
                if (act)  v = gelu_tanh(v);
                if (res)  v += res[(size_t)m * N + n];
                if (mode == 2) {
                    if (n < 512) Cb[(size_t)m * 512 + n] = __float2bfloat16(v + bias_u[n]);
                    else Cb2[(size_t)m * 512 + (n - 512)] = __float2bfloat16(v + bias_v[n - 512]);
                } else if (mode == 1) {
                    Cb[(size_t)m * N + n]  = __float2bfloat16(v + bias_u[n]);
                    Cb2[(size_t)m * N + n] = __float2bfloat16(v + bias_v[n]);
                } else {
                    if (Cf) Cf[(size_t)m * N + n] = v;
                    if (Cb) Cb[(size_t)m * N + n] = __float2bfloat16(v);
                }
            }
        }
    }
}

// ---------------- standalone GEMM (encoder / Wo / W1 / W2) -------------------
__global__ __launch_bounds__(256) void mfma_gemm_kernel(
    const bf16* __restrict__ A, const bf16* __restrict__ Bt,
    const float* __restrict__ bias, const float* __restrict__ res,
    float* __restrict__ Cf, bf16* __restrict__ Cb,
    int K, int N, int act)
{
    __shared__ short As[128 * 72];
    __shared__ short Bs[64 * 72];
    gemm_body(As, Bs, A, Bt, blockIdx.y * 128, blockIdx.x * 64, K, N,
              bias, nullptr, nullptr, res, Cf, Cb, nullptr, act, 0);
}

// ---------------- fused Q + KV + R projection (one dispatch) -----------------
__global__ __launch_bounds__(256) void qkvr_kernel(
    const bf16* __restrict__ QN, const bf16* __restrict__ VK,
    const bf16* __restrict__ PE_, const bf16* __restrict__ WqT,
    const bf16* __restrict__ WkvT, const bf16* __restrict__ WrT,
    const float* __restrict__ bq, const float* __restrict__ ub,
    const float* __restrict__ vbias, const float* __restrict__ bk,
    const float* __restrict__ bv,
    bf16* __restrict__ QU, bf16* __restrict__ QV,
    bf16* __restrict__ KB, bf16* __restrict__ VB, bf16* __restrict__ RB)
{
    __shared__ short As[128 * 72];
    __shared__ short Bs[64 * 72];
    const int bid = blockIdx.x;
    if (bid < 256) {
        const int mblk = bid >> 3, nblk = bid & 7;
        gemm_body(As, Bs, QN, WqT, mblk * 128, nblk * 64, E, E,
                  bq, ub, vbias, nullptr, nullptr, QU, QV, 0, 1);
    } else if (bid < 1280) {
        const int id = bid - 256;
        const int mblk = id >> 4, nblk = id & 15;
        gemm_body(As, Bs, VK, WkvT, mblk * 128, nblk * 64, E, 2 * E,
                  nullptr, bk, bv, nullptr, nullptr, KB, VB, 0, 2);
    } else {
        const int id = bid - 1280;
        const int mblk = id >> 3, nblk = id & 7;
        gemm_body(As, Bs, PE_, WrT, mblk * 128, nblk * 64, E, E,
                  nullptr, nullptr, nullptr, nullptr, nullptr, RB, nullptr, 0, 0);
    }
}

// ---------------- merged LN pass 1 (memories + x) ----------------------------
__global__ __launch_bounds__(256) void ln1_kernel(
    const float* __restrict__ mem, const float* __restrict__ X, int li,
    const float* __restrict__ gam, const float* __restrict__ bet,
    bf16* __restrict__ qn, bf16* __restrict__ vkdst)
{
    const int blk = blockIdx.x;
    const int t = threadIdx.x;
    const bool isMem = blk < B * MEM;
    const int rr = isMem ? blk : (blk - B * MEM);
    const float* sp = isMem ? (mem + ((size_t)rr * L + li) * E)
                            : (X + (size_t)rr * E);
    const float x0 = sp[t], x1 = sp[t + 256];
    float s = x0 + x1, ss = fmaf(x0, x0, x1 * x1);
    #pragma unroll
    for (int off = 32; off; off >>= 1) { s += __shfl_down(s, off, 64); ss += __shfl_down(ss, off, 64); }
    __shared__ float tmp[8];
    const int wid = t >> 6, lane = t & 63;
    if (!lane) { tmp[wid] = s; tmp[4 + wid] = ss; }
    __syncthreads();
    s = tmp[0] + tmp[1] + tmp[2] + tmp[3];
    ss = tmp[4] + tmp[5] + tmp[6] + tmp[7];
    const float mean = s * (1.0f / E);
    const float var = ss * (1.0f / E) - mean * mean;
    const float rstd = rsqrtf(var + 1e-6f);
    const float y0 = (x0 - mean) * rstd * gam[t] + bet[t];
    const float y1 = (x1 - mean) * rstd * gam[t + 256] + bet[t + 256];
    const int b = rr >> 9, p = rr & 511;
    if (isMem) {
        bf16* dst = vkdst + ((size_t)b * KLEN + p) * E;
        dst[t] = __float2bfloat16(y0); dst[t + 256] = __float2bfloat16(y1);
    } else {
        qn[(size_t)rr * E + t]       = __float2bfloat16(y0);
        qn[(size_t)rr * E + t + 256] = __float2bfloat16(y1);
        bf16* d2 = vkdst + ((size_t)b * KLEN + MEM + p) * E;
        d2[t] = __float2bfloat16(y0); d2[t + 256] = __float2bfloat16(y1);
    }
}

// ---------------- LN (fp32 src -> bf16 dst), used for ln2 --------------------
__global__ __launch_bounds__(256) void ln_f32_kernel(
    const float* __restrict__ src,
    const float* __restrict__ gam, const float* __restrict__ bet,
    bf16* __restrict__ dst1)
{
    const int rr = blockIdx.x;
    const int t = threadIdx.x;
    const float* sp = src + (size_t)rr * E;
    const float x0 = sp[t], x1 = sp[t + 256];
    float s = x0 + x1, ss = fmaf(x0, x0, x1 * x1);
    #pragma unroll
    for (int off = 32; off; off >>= 1) { s += __shfl_down(s, off, 64); ss += __shfl_down(ss, off, 64); }
    __shared__ float tmp[8];
    const int wid = t >> 6, lane = t & 63;
    if (!lane) { tmp[wid] = s; tmp[4 + wid] = ss; }
    __syncthreads();
    s = tmp[0] + tmp[1] + tmp[2] + tmp[3];
    ss = tmp[4] + tmp[5] + tmp[6] + tmp[7];
    const float mean = s * (1.0f / E);
    const float var = ss * (1.0f / E) - mean * mean;
    const float rstd = rsqrtf(var + 1e-6f);
    dst1[(size_t)rr * E + t]       = __float2bfloat16((x0 - mean) * rstd * gam[t] + bet[t]);
    dst1[(size_t)rr * E + t + 256] = __float2bfloat16((x1 - mean) * rstd * gam[t + 256] + bet[t + 256]);
}

// ---------------- MFMA flash attention, BARRIER-FREE -------------------------
// block=(qt,h,b) with qt work-balance swizzle; 64 q rows (4 waves x 16).
// K/V/R fragments loaded DIRECTLY from global (L2-resident, B-frag pattern);
// only wave-private LDS (BDs, Ps) remains -> zero __syncthreads in the loop.
// score = (Qu·K^T + Qv·R[k+511-q]) * 0.125, mask k <= 512+q.
__global__ __launch_bounds__(256) void mfma_flash_kernel(
    const bf16* __restrict__ Qu,   // [B*S][E]
    const bf16* __restrict__ Qv,   // [B*S][E]
    const bf16* __restrict__ Kb,   // [B*KLEN][E]
    const bf16* __restrict__ Vt,   // [B][E][KLEN]
    const bf16* __restrict__ Rb,   // [KLEN][E]
    bf16* __restrict__ O)          // [B*S][E]
{
    const int qphys = blockIdx.x, h = blockIdx.y, b = blockIdx.z;
    // pair long and short blocks: (0,7),(1,6),(2,5),(3,4) -> equal 25-tile pairs
    const int qt = (qphys & 1) ? (7 - (qphys >> 1)) : (qphys >> 1);
    const int q0 = qt * FQ;
    const int t = threadIdx.x;
    const int w = t >> 6, lane = t & 63;
    const int fr = lane & 15, quad = lane >> 4;
    const int qbase = q0 + w * 16;

    __shared__ short BDs[4][80][20];   // per-wave BD transposed [jlr][qw]
    __shared__ short Ps[4][16][72];    // per-wave P

    // Q A-frags straight from global (one-time)
    const short* quptr = (const short*)Qu + ((size_t)(b * S + qbase + fr)) * E + h * DH + quad * 8;
    const frag_ab au0 = *(const frag_ab*)(quptr);
    const frag_ab au1 = *(const frag_ab*)(quptr + 32);
    const short* qvptr = (const short*)Qv + ((size_t)(b * S + qbase + fr)) * E + h * DH + quad * 8;
    const frag_ab av0 = *(const frag_ab*)(qvptr);
    const frag_ab av1 = *(const frag_ab*)(qvptr + 32);

    frag_cd accO[4];
    #pragma unroll
    for (int i = 0; i < 4; ++i) accO[i] = (frag_cd)(0.0f);
    float mrow[4] = {-3.0e38f, -3.0e38f, -3.0e38f, -3.0e38f};
    float lrow[4] = {0.f, 0.f, 0.f, 0.f};

    // direct-global fragment base pointers (all 16B-aligned)
    const short* kbase = (const short*)Kb + ((size_t)(b * KLEN)) * E + h * DH + quad * 8;
    const short* vbase = (const short*)Vt + ((size_t)(b * E + h * DH)) * KLEN + quad * 8;
    const short* rbase = (const short*)Rb + h * DH + quad * 8;
    const int ntb0 = 3 - w;            // wave BD window: n-tiles ntb0..ntb0+4
    const int b0 = 448 - q0;           // R band origin at kt=0 (0..448)

    const int ntiles = 9 + qt;
    for (int kt = 0; kt < ntiles; ++kt) {
        const int k0 = kt * FK;

        // ---- BD tiles: BDs[w][jlr][qw] = Qv·R^T (wave's 80-col window) ----
        #pragma unroll
        for (int i = 0; i < 5; ++i) {
            int j = b0 + k0 + (ntb0 + i) * 16 + fr;
            if (j > KLEN - 1) j = KLEN - 1;   // clamped rows feed masked scores only
            const short* rp = rbase + (size_t)j * E;
            const frag_ab rf0 = *(const frag_ab*)(rp);
            const frag_ab rf1 = *(const frag_ab*)(rp + 32);
            frag_cd z = (frag_cd)(0.0f);
            z = __builtin_amdgcn_mfma_f32_16x16x32_bf16(av0, rf0, z, 0, 0, 0);
            z = __builtin_amdgcn_mfma_f32_16x16x32_bf16(av1, rf1, z, 0, 0, 0);
            union { uint2 u; unsigned short sh[4]; } pk;
            pk.sh[0] = f2bs(z[0]); pk.sh[1] = f2bs(z[1]);
            pk.sh[2] = f2bs(z[2]); pk.sh[3] = f2bs(z[3]);
            *(uint2*)&BDs[w][i * 16 + fr][quad * 4] = pk.u;
        }

        // ---- S = Qu·K^T (K frags direct from global) ----
        frag_cd sc[4];
        #pragma unroll
        for (int nt = 0; nt < 4; ++nt) {
            const short* kp = kbase + (size_t)(k0 + nt * 16 + fr) * E;
            const frag_ab kf0 = *(const frag_ab*)(kp);
            const frag_ab kf1 = *(const frag_ab*)(kp + 32);
            frag_cd z = (frag_cd)(0.0f);
            z = __builtin_amdgcn_mfma_f32_16x16x32_bf16(au0, kf0, z, 0, 0, 0);
            z = __builtin_amdgcn_mfma_f32_16x16x32_bf16(au1, kf1, z, 0, 0, 0);
            sc[nt] = z;
        }

        // ---- +BD (from LDS), mask, online softmax per C-row ----
        #pragma unroll
        for (int r = 0; r < 4; ++r) {
            const int qw = quad * 4 + r;
            const int qrow = qbase + qw;
            float sv[4];
            #pragma unroll
            for (int nt = 0; nt < 4; ++nt) {
                const int kcol = k0 + nt * 16 + fr;
                const int jlr = nt * 16 + fr + 15 - qw;   // 0..78
                const float bd = bs2f(BDs[w][jlr][qw]);
                const float sval = (sc[nt][r] + bd) * 0.125f;
                sv[nt] = (kcol <= MEM + qrow) ? sval : -1e30f;
            }
            float tm = fmaxf(fmaxf(sv[0], sv[1]), fmaxf(sv[2], sv[3]));
            tm = fmaxf(tm, __shfl_xor(tm, 1, 64));
            tm = fmaxf(tm, __shfl_xor(tm, 2, 64));
            tm = fmaxf(tm, __shfl_xor(tm, 4, 64));
            tm = fmaxf(tm, __shfl_xor(tm, 8, 64));
            const float mn = fmaxf(mrow[r], tm);
            const float p0 = __expf(sv[0] - mn), p1 = __expf(sv[1] - mn);
            const float p2 = __expf(sv[2] - mn), p3 = __expf(sv[3] - mn);
            float wsum = p0 + p1 + p2 + p3;
            wsum += __shfl_xor(wsum, 1, 64);
            wsum += __shfl_xor(wsum, 2, 64);
            wsum += __shfl_xor(wsum, 4, 64);
            wsum += __shfl_xor(wsum, 8, 64);
            const float al = __expf(mrow[r] - mn);
            lrow[r] = lrow[r] * al + wsum;
            mrow[r] = mn;
            #pragma unroll
            for (int nt = 0; nt < 4; ++nt) accO[nt][r] *= al;
            Ps[w][qw][fr]      = (short)f2bs(p0);
            Ps[w][qw][16 + fr] = (short)f2bs(p1);
            Ps[w][qw][32 + fr] = (short)f2bs(p2);
            Ps[w][qw][48 + fr] = (short)f2bs(p3);
        }

        // ---- O += P·V (P same-wave LDS; V frags direct from global) ----
        const frag_ab pf0 = *(const frag_ab*)&Ps[w][fr][quad * 8];
        const frag_ab pf1 = *(const frag_ab*)&Ps[w][fr][32 + quad * 8];
        #pragma unroll
        for (int nt = 0; nt < 4; ++nt) {
            const short* vp = vbase + (size_t)(nt * 16 + fr) * KLEN + k0;
            const frag_ab vf0 = *(const frag_ab*)(vp);
            const frag_ab vf1 = *(const frag_ab*)(vp + 32);
            accO[nt] = __builtin_amdgcn_mfma_f32_16x16x32_bf16(pf0, vf0, accO[nt], 0, 0, 0);
            accO[nt] = __builtin_amdgcn_mfma_f32_16x16x32_bf16(pf1, vf1, accO[nt], 0, 0, 0);
        }
    }

    #pragma unroll
    for (int r = 0; r < 4; ++r) {
        const float inv = 1.0f / lrow[r];
        bf16* po = O + ((size_t)(b * S + qbase + quad * 4 + r)) * E + h * DH + fr;
        #pragma unroll
        for (int nt = 0; nt < 4; ++nt)
            po[nt * 16] = __float2bfloat16(accO[nt][r] * inv);
    }
}

extern "C" void kernel_launch(void* const* d_in, const int* in_sizes, int n_in,
                              void* d_out, int out_size, void* d_ws, size_t ws_size,
                              hipStream_t stream)
{
    const float* obs  = (const float*)d_in[0];
    const float* mem  = (const float*)d_in[1];
    // d_in[2] = mask: deterministic (k <= MEM + q), recomputed in-kernel
    const float* Wenc = (const float*)d_in[3];
    const float* benc = (const float*)d_in[4];
    const float* ln1s = (const float*)d_in[5];
    const float* ln1b = (const float*)d_in[6];
    const float* Wq   = (const float*)d_in[7];
    const float* bq   = (const float*)d_in[8];
    const float* Wk   = (const float*)d_in[9];
    const float* bk   = (const float*)d_in[10];
    const float* Wv   = (const float*)d_in[11];
    const float* bv   = (const float*)d_in[12];
    const float* Wr   = (const float*)d_in[13];
    const float* ub   = (const float*)d_in[14];
    const float* vb   = (const float*)d_in[15];
    const float* Wo   = (const float*)d_in[16];
    const float* bo   = (const float*)d_in[17];
    const float* ln2s = (const float*)d_in[18];
    const float* ln2b = (const float*)d_in[19];
    const float* W1   = (const float*)d_in[20];
    const float* b1   = (const float*)d_in[21];
    const float* W2   = (const float*)d_in[22];
    const float* b2   = (const float*)d_in[23];

    // ---- workspace ----
    float* wsf = (float*)d_ws;
    float* X = wsf;                                   // fp32 [B*S*E]
    bf16* wsb = (bf16*)(wsf + (size_t)B * S * E);
    size_t ob = 0;
    bf16* OBSb = wsb + ob; ob += (size_t)B * S * OBS;
    bf16* QNb  = wsb + ob; ob += (size_t)B * S * E;
    bf16* PEb  = wsb + ob; ob += (size_t)KLEN * E;
    bf16* RBb  = wsb + ob; ob += (size_t)KLEN * E;
    bf16* WencT= wsb + ob; ob += (size_t)OBS * E;
    bf16* WqT  = wsb + ob; ob += (size_t)L * E * E;
    bf16* WkvT = wsb + ob; ob += (size_t)L * 2 * E * E;   // [L][1024][512]
    bf16* WrT  = wsb + ob; ob += (size_t)L * E * E;
    bf16* WoT  = wsb + ob; ob += (size_t)L * E * E;
    bf16* W1T  = wsb + ob; ob += (size_t)L * E * E;
    bf16* W2T  = wsb + ob; ob += (size_t)L * E * E;
    bf16* QUb  = wsb + ob; ob += (size_t)B * S * E;
    bf16* QVb  = wsb + ob; ob += (size_t)B * S * E;
    bf16* KBb  = wsb + ob; ob += (size_t)B * KLEN * E;
    bf16* VTb  = wsb + ob; ob += (size_t)B * E * KLEN;
    bf16* OBb  = wsb + ob; ob += (size_t)B * S * E;
    // union: {VKb, VBb} ∪ {HB, FFb} (disjoint lifetimes per layer)
    char* uni = (char*)(wsb + ob);
    bf16*  VKb = (bf16*)uni;                          // [B*KLEN][E] (8 MB) @0
    bf16*  VBb = (bf16*)(uni + ((size_t)8 << 20));    // [B*KLEN][E] (8 MB) @8M
    float* HB  = (float*)uni;                         // [B*S][E] fp32 (8 MB) @0
    bf16*  FFb = (bf16*)(uni + ((size_t)8 << 20));    // [B*S][E] (4 MB) @8M

    // ---- setup: merged weight transposes, obs cast + pe ----
    transpose_all_kernel<<<dim3(E / 32, E / 32, 29), 256, 0, stream>>>(
        Wq, Wk, Wv, Wr, Wo, W1, W2, Wenc, WqT, WkvT, WrT, WoT, W1T, W2T, WencT);
    setup_kernel<<<(B * S * OBS + KLEN * E) / 256, 256, 0, stream>>>(obs, OBSb, PEb);

    // encoder: X = obs @ W_enc + b_enc (fp32)
    mfma_gemm_kernel<<<dim3(E / 64, (B * S) / 128), 256, 0, stream>>>(
        OBSb, WencT, benc, nullptr, X, nullptr, OBS, E, 0);

    for (int li = 0; li < L; ++li) {
        const size_t wOff = (size_t)li * E * E;
        const size_t vOff = (size_t)li * E;

        ln1_kernel<<<2 * B * S, 256, 0, stream>>>(
            mem, X, li, ln1s + vOff, ln1b + vOff, QNb, VKb);

        qkvr_kernel<<<1344, 256, 0, stream>>>(
            QNb, VKb, PEb, WqT + wOff, WkvT + (size_t)li * 2 * E * E, WrT + wOff,
            bq + vOff, ub + vOff, vb + vOff, bk + vOff, bv + vOff,
            QUb, QVb, KBb, VBb, RBb);

        transpose_v_kernel<<<dim3(KLEN / 64, E / 64, B), 256, 0, stream>>>(VBb, VTb);

        mfma_flash_kernel<<<dim3(S / FQ, H, B), 256, 0, stream>>>(
            QUb, QVb, KBb, VTb, RBb, OBb);

        // HB = X + (O @ Wo + bo)
        mfma_gemm_kernel<<<dim3(E / 64, (B * S) / 128), 256, 0, stream>>>(
            OBb, WoT + wOff, bo + vOff, X, HB, nullptr, E, E, 0);
        ln_f32_kernel<<<B * S, 256, 0, stream>>>(HB, ln2s + vOff, ln2b + vOff, QNb);
        // FFb = gelu(hn @ W1 + b1)
        mfma_gemm_kernel<<<dim3(E / 64, (B * S) / 128), 256, 0, stream>>>(
            QNb, W1T + wOff, b1 + vOff, nullptr, nullptr, FFb, E, E, 1);
        // X = FF @ W2 + b2 + HB
        mfma_gemm_kernel<<<dim3(E / 64, (B * S) / 128), 256, 0, stream>>>(
            FFb, W2T + wOff, b2 + vOff, HB, X, nullptr, E, E, 0);
    }

    hipMemcpyAsync(d_out, X, (size_t)B * S * E * sizeof(float),
                   hipMemcpyDeviceToDevice, stream);
}

// Round 10
// 825.484 us; speedup vs baseline: 1.2831x; 1.2831x over previous
//
#include <hip/hip_runtime.h>
#include <hip/hip_bf16.h>
#include <math.h>

#define B     8
#define S     512
#define MEM   512
#define L     4
#define E     512
#define H     8
#define DH    64
#define OBS   128
#define KLEN  1024   // MEM + S
#define FQ    64     // flash: q rows per block
#define FK    64     // flash: k per tile

typedef __hip_bfloat16 bf16;
using frag_ab = __attribute__((ext_vector_type(8))) short;   // 8 bf16 (4 VGPRs)
using frag_cd = __attribute__((ext_vector_type(4))) float;   // 4 fp32 acc

__device__ __forceinline__ float gelu_tanh(float x) {
    return 0.5f * x * (1.0f + tanhf(0.7978845608028654f * (x + 0.044715f * x * x * x)));
}
__device__ __forceinline__ unsigned short f2bs(float x) {
    bf16 h = __float2bfloat16(x); return *(unsigned short*)&h;
}
__device__ __forceinline__ float bs2f(short s) {
    union { unsigned u; float f; } t; t.u = ((unsigned)(unsigned short)s) << 16; return t.f;
}

// ---------------- merged setup: obs cast + positional embedding --------------
__global__ __launch_bounds__(256) void setup_kernel(
    const float* __restrict__ obs, bf16* __restrict__ obsb, bf16* __restrict__ pe)
{
    const int i = blockIdx.x * 256 + threadIdx.x;
    if (i < B * S * OBS) {
        obsb[i] = __float2bfloat16(obs[i]);
    } else {
        const int idx = i - B * S * OBS;
        const int p = idx >> 9;
        const int j = idx & 511;
        const float pos = (float)(KLEN - p);
        const int m = (j < 256) ? j : (j - 256);
        const float invf = expf(-(float)(2 * m) * (9.210340371976184f / (float)E));
        const float a = pos * invf;
        pe[idx] = __float2bfloat16((j < 256) ? sinf(a) : cosf(a));
    }
}

// ------- merged weight transposes: z = which*4 + li; z==28 -> Wenc -----------
__global__ __launch_bounds__(256) void transpose_all_kernel(
    const float* __restrict__ Wq, const float* __restrict__ Wk,
    const float* __restrict__ Wv, const float* __restrict__ Wr,
    const float* __restrict__ Wo, const float* __restrict__ W1,
    const float* __restrict__ W2, const float* __restrict__ Wenc,
    bf16* __restrict__ WqT, bf16* __restrict__ WkvT, bf16* __restrict__ WrT,
    bf16* __restrict__ WoT, bf16* __restrict__ W1T, bf16* __restrict__ W2T,
    bf16* __restrict__ WencT)
{
    __shared__ float t[32][33];
    const int z = blockIdx.z;
    const int bn = blockIdx.x * 32, bk = blockIdx.y * 32;
    const int tx = threadIdx.x & 31, ty = threadIdx.x >> 5;
    if (z == 28) {                         // Wenc: [OBS][E] -> [E][OBS]
        if (blockIdx.y >= OBS / 32) return;
        #pragma unroll
        for (int r = 0; r < 32; r += 8)
            t[ty + r][tx] = Wenc[(size_t)(bk + ty + r) * E + bn + tx];
        __syncthreads();
        #pragma unroll
        for (int r = 0; r < 32; r += 8)
            WencT[(size_t)(bn + ty + r) * OBS + bk + tx] = __float2bfloat16(t[tx][ty + r]);
        return;
    }
    const int which = z >> 2, li = z & 3;
    const size_t so = (size_t)li * E * E;
    const float* src; bf16* dst;
    switch (which) {
        case 0: src = Wq + so; dst = WqT + so; break;
        case 1: src = Wk + so; dst = WkvT + (size_t)li * 2 * E * E; break;
        case 2: src = Wv + so; dst = WkvT + (size_t)li * 2 * E * E + (size_t)E * E; break;
        case 3: src = Wr + so; dst = WrT + so; break;
        case 4: src = Wo + so; dst = WoT + so; break;
        case 5: src = W1 + so; dst = W1T + so; break;
        default: src = W2 + so; dst = W2T + so; break;
    }
    #pragma unroll
    for (int r = 0; r < 32; r += 8)
        t[ty + r][tx] = src[(size_t)(bk + ty + r) * E + bn + tx];
    __syncthreads();
    #pragma unroll
    for (int r = 0; r < 32; r += 8)
        dst[(size_t)(bn + ty + r) * E + bk + tx] = __float2bfloat16(t[tx][ty + r]);
}

// ---------------- V transpose: Vn[B*KLEN][E] bf16 -> Vt[B][E][KLEN] bf16 -----
__global__ __launch_bounds__(256) void transpose_v_kernel(
    const bf16* __restrict__ Vn, bf16* __restrict__ Vt)
{
    __shared__ short ts[64][72];
    const int k0 = blockIdx.x * 64, d0 = blockIdx.y * 64, b = blockIdx.z;
    const int t = threadIdx.x;
    const int r = t >> 2, c = (t & 3) * 16;
    const short* src = (const short*)Vn + ((size_t)(b * KLEN + k0 + r)) * E + d0 + c;
    *(uint4*)&ts[r][c]     = *(const uint4*)(src);
    *(uint4*)&ts[r][c + 8] = *(const uint4*)(src + 8);
    __syncthreads();
    short vals[16];
    #pragma unroll
    for (int i = 0; i < 16; ++i) vals[i] = ts[c + i][r];
    short* dst = (short*)Vt + ((size_t)(b * E + d0 + r)) * KLEN + k0 + c;
    *(uint4*)(dst)     = *(const uint4*)&vals[0];
    *(uint4*)(dst + 8) = *(const uint4*)&vals[8];
}

// ---------------- GEMM tile body: 128m x 64n, BK=64, 4 waves of 64x32 --------
__device__ __forceinline__ void gemm_body(
    short* As, short* Bs,
    const bf16* __restrict__ A, const bf16* __restrict__ Bt,
    int m0, int n0, int K, int N,
    const float* bias, const float* bias_u, const float* bias_v,
    const float* res, float* Cf, bf16* Cb, bf16* Cb2, int act, int mode)
{
    const int tid = threadIdx.x;
    const int w = tid >> 6, lane = tid & 63;
    const int wm2 = (w >> 1) * 64, wn2 = (w & 1) * 32;
    const int fr = lane & 15, quad = lane >> 4;

    const int arow = tid >> 1, acol = (tid & 1) * 32;
    const int brow = tid >> 2, bcol = (tid & 3) * 16;
    const short* Ag = (const short*)A + (size_t)(m0 + arow) * K + acol;
    const short* Bg = (const short*)Bt + (size_t)(n0 + brow) * K + bcol;
    short* Asw = &As[arow * 72 + acol];
    short* Bsw = &Bs[brow * 72 + bcol];

    frag_cd acc[4][2];
    #pragma unroll
    for (int i = 0; i < 4; ++i)
        #pragma unroll
        for (int j = 0; j < 2; ++j)
            acc[i][j] = (frag_cd)(0.0f);

    for (int k0 = 0; k0 < K; k0 += 64) {
        const uint4 a0 = *(const uint4*)(Ag + k0);
        const uint4 a1 = *(const uint4*)(Ag + k0 + 8);
        const uint4 a2 = *(const uint4*)(Ag + k0 + 16);
        const uint4 a3 = *(const uint4*)(Ag + k0 + 24);
        const uint4 b0 = *(const uint4*)(Bg + k0);
        const uint4 b1 = *(const uint4*)(Bg + k0 + 8);
        __syncthreads();
        *(uint4*)(Asw) = a0; *(uint4*)(Asw + 8) = a1;
        *(uint4*)(Asw + 16) = a2; *(uint4*)(Asw + 24) = a3;
        *(uint4*)(Bsw) = b0; *(uint4*)(Bsw + 8) = b1;
        __syncthreads();
        #pragma unroll
        for (int kh = 0; kh < 2; ++kh) {
            frag_ab af[4], bfr[2];
            #pragma unroll
            for (int i = 0; i < 4; ++i)
                af[i] = *(const frag_ab*)&As[(wm2 + i * 16 + fr) * 72 + kh * 32 + quad * 8];
            #pragma unroll
            for (int j = 0; j < 2; ++j)
                bfr[j] = *(const frag_ab*)&Bs[(wn2 + j * 16 + fr) * 72 + kh * 32 + quad * 8];
            #pragma unroll
            for (int i = 0; i < 4; ++i)
                #pragma unroll
                for (int j = 0; j < 2; ++j)
                    acc[i][j] = __builtin_amdgcn_mfma_f32_16x16x32_bf16(af[i], bfr[j], acc[i][j], 0, 0, 0);
        }
    }

    #pragma unroll
    for (int i = 0; i < 4; ++i) {
        #pragma unroll
        for (int r = 0; r < 4; ++r) {
            const int m = m0 + wm2 + i * 16 + quad * 4 + r;
            #pragma unroll
            for (int j = 0; j < 2; ++j) {
                const int n = n0 + wn2 + j * 16 + fr;
                float v = acc[i][j][r];
                if (bias) v += bias[n];
                if (act)  v = gelu_tanh(v);
                if (res)  v += res[(size_t)m * N + n];
                if (mode == 2) {
                    if (n < 512) Cb[(size_t)m * 512 + n] = __float2bfloat16(v + bias_u[n]);
                    else Cb2[(size_t)m * 512 + (n - 512)] = __float2bfloat16(v + bias_v[n - 512]);
                } else if (mode == 1) {
                    Cb[(size_t)m * N + n]  = __float2bfloat16(v + bias_u[n]);
                    Cb2[(size_t)m * N + n] = __float2bfloat16(v + bias_v[n]);
                } else {
                    if (Cf) Cf[(size_t)m * N + n] = v;
                    if (Cb) Cb[(size_t)m * N + n] = __float2bfloat16(v);
                }
            }
        }
    }
}

// ---------------- standalone GEMM (encoder / Wo / W1 / W2) -------------------
__global__ __launch_bounds__(256) void mfma_gemm_kernel(
    const bf16* __restrict__ A, const bf16* __restrict__ Bt,
    const float* __restrict__ bias, const float* __restrict__ res,
    float* __restrict__ Cf, bf16* __restrict__ Cb,
    int K, int N, int act)
{
    __shared__ short As[128 * 72];
    __shared__ short Bs[64 * 72];
    gemm_body(As, Bs, A, Bt, blockIdx.y * 128, blockIdx.x * 64, K, N,
              bias, nullptr, nullptr, res, Cf, Cb, nullptr, act, 0);
}

// ---------------- fused Q + KV + R projection (one dispatch) -----------------
__global__ __launch_bounds__(256) void qkvr_kernel(
    const bf16* __restrict__ QN, const bf16* __restrict__ VK,
    const bf16* __restrict__ PE_, const bf16* __restrict__ WqT,
    const bf16* __restrict__ WkvT, const bf16* __restrict__ WrT,
    const float* __restrict__ bq, const float* __restrict__ ub,
    const float* __restrict__ vbias, const float* __restrict__ bk,
    const float* __restrict__ bv,
    bf16* __restrict__ QU, bf16* __restrict__ QV,
    bf16* __restrict__ KB, bf16* __restrict__ VB, bf16* __restrict__ RB)
{
    __shared__ short As[128 * 72];
    __shared__ short Bs[64 * 72];
    const int bid = blockIdx.x;
    if (bid < 256) {
        const int mblk = bid >> 3, nblk = bid & 7;
        gemm_body(As, Bs, QN, WqT, mblk * 128, nblk * 64, E, E,
                  bq, ub, vbias, nullptr, nullptr, QU, QV, 0, 1);
    } else if (bid < 1280) {
        const int id = bid - 256;
        const int mblk = id >> 4, nblk = id & 15;
        gemm_body(As, Bs, VK, WkvT, mblk * 128, nblk * 64, E, 2 * E,
                  nullptr, bk, bv, nullptr, nullptr, KB, VB, 0, 2);
    } else {
        const int id = bid - 1280;
        const int mblk = id >> 3, nblk = id & 7;
        gemm_body(As, Bs, PE_, WrT, mblk * 128, nblk * 64, E, E,
                  nullptr, nullptr, nullptr, nullptr, nullptr, RB, nullptr, 0, 0);
    }
}

// ---------------- merged LN pass 1 (memories + x) ----------------------------
__global__ __launch_bounds__(256) void ln1_kernel(
    const float* __restrict__ mem, const float* __restrict__ X, int li,
    const float* __restrict__ gam, const float* __restrict__ bet,
    bf16* __restrict__ qn, bf16* __restrict__ vkdst)
{
    const int blk = blockIdx.x;
    const int t = threadIdx.x;
    const bool isMem = blk < B * MEM;
    const int rr = isMem ? blk : (blk - B * MEM);
    const float* sp = isMem ? (mem + ((size_t)rr * L + li) * E)
                            : (X + (size_t)rr * E);
    const float x0 = sp[t], x1 = sp[t + 256];
    float s = x0 + x1, ss = fmaf(x0, x0, x1 * x1);
    #pragma unroll
    for (int off = 32; off; off >>= 1) { s += __shfl_down(s, off, 64); ss += __shfl_down(ss, off, 64); }
    __shared__ float tmp[8];
    const int wid = t >> 6, lane = t & 63;
    if (!lane) { tmp[wid] = s; tmp[4 + wid] = ss; }
    __syncthreads();
    s = tmp[0] + tmp[1] + tmp[2] + tmp[3];
    ss = tmp[4] + tmp[5] + tmp[6] + tmp[7];
    const float mean = s * (1.0f / E);
    const float var = ss * (1.0f / E) - mean * mean;
    const float rstd = rsqrtf(var + 1e-6f);
    const float y0 = (x0 - mean) * rstd * gam[t] + bet[t];
    const float y1 = (x1 - mean) * rstd * gam[t + 256] + bet[t + 256];
    const int b = rr >> 9, p = rr & 511;
    if (isMem) {
        bf16* dst = vkdst + ((size_t)b * KLEN + p) * E;
        dst[t] = __float2bfloat16(y0); dst[t + 256] = __float2bfloat16(y1);
    } else {
        qn[(size_t)rr * E + t]       = __float2bfloat16(y0);
        qn[(size_t)rr * E + t + 256] = __float2bfloat16(y1);
        bf16* d2 = vkdst + ((size_t)b * KLEN + MEM + p) * E;
        d2[t] = __float2bfloat16(y0); d2[t + 256] = __float2bfloat16(y1);
    }
}

// ---------------- LN (fp32 src -> bf16 dst), used for ln2 --------------------
__global__ __launch_bounds__(256) void ln_f32_kernel(
    const float* __restrict__ src,
    const float* __restrict__ gam, const float* __restrict__ bet,
    bf16* __restrict__ dst1)
{
    const int rr = blockIdx.x;
    const int t = threadIdx.x;
    const float* sp = src + (size_t)rr * E;
    const float x0 = sp[t], x1 = sp[t + 256];
    float s = x0 + x1, ss = fmaf(x0, x0, x1 * x1);
    #pragma unroll
    for (int off = 32; off; off >>= 1) { s += __shfl_down(s, off, 64); ss += __shfl_down(ss, off, 64); }
    __shared__ float tmp[8];
    const int wid = t >> 6, lane = t & 63;
    if (!lane) { tmp[wid] = s; tmp[4 + wid] = ss; }
    __syncthreads();
    s = tmp[0] + tmp[1] + tmp[2] + tmp[3];
    ss = tmp[4] + tmp[5] + tmp[6] + tmp[7];
    const float mean = s * (1.0f / E);
    const float var = ss * (1.0f / E) - mean * mean;
    const float rstd = rsqrtf(var + 1e-6f);
    dst1[(size_t)rr * E + t]       = __float2bfloat16((x0 - mean) * rstd * gam[t] + bet[t]);
    dst1[(size_t)rr * E + t + 256] = __float2bfloat16((x1 - mean) * rstd * gam[t + 256] + bet[t + 256]);
}

// ---------------- MFMA flash attention (LDS-staged, TRANSPOSED softmax) ------
// block=(qt,h,b) with qt work-balance swizzle; 64 q rows (4 waves x 16).
// S^T = K·Qu^T and BD^T = R·Qv^T so each lane's 16 scores share q = lane&15:
// softmax is in-lane + 2 shuffles; P written as b64; m/l one scalar per lane.
// score = (Qu·K^T + Qv·R[k+511-q]) * 0.125, mask k <= 512+q.
__global__ __launch_bounds__(256) void mfma_flash_kernel(
    const bf16* __restrict__ Qu,   // [B*S][E]
    const bf16* __restrict__ Qv,   // [B*S][E]
    const bf16* __restrict__ Kb,   // [B*KLEN][E]
    const bf16* __restrict__ Vt,   // [B][E][KLEN]
    const bf16* __restrict__ Rb,   // [KLEN][E]
    bf16* __restrict__ O)          // [B*S][E]
{
    const int qphys = blockIdx.x, h = blockIdx.y, b = blockIdx.z;
    const int qt = (qphys & 1) ? (7 - (qphys >> 1)) : (qphys >> 1);
    const int q0 = qt * FQ;
    const int t = threadIdx.x;
    const int w = t >> 6, lane = t & 63;
    const int fr = lane & 15, quad = lane >> 4;
    const int qbase = q0 + w * 16;

    __shared__ short Ks[FK][72];
    __shared__ short Vs[64][72];       // [d][k]
    __shared__ short Rs[128][72];      // circular R band, slot = j & 127
    __shared__ short BDs[4][16][84];   // per-wave BD^T as [q][si], si = 0..79
    __shared__ short Ps[4][16][72];    // per-wave P as [q][k]

    // Qu/Qv fragments (B-operand layout; one-time)
    const short* quptr = (const short*)Qu + ((size_t)(b * S + qbase + fr)) * E + h * DH + quad * 8;
    const frag_ab au0 = *(const frag_ab*)(quptr);
    const frag_ab au1 = *(const frag_ab*)(quptr + 32);
    const short* qvptr = (const short*)Qv + ((size_t)(b * S + qbase + fr)) * E + h * DH + quad * 8;
    const frag_ab av0 = *(const frag_ab*)(qvptr);
    const frag_ab av1 = *(const frag_ab*)(qvptr + 32);

    frag_cd accO[4];
    #pragma unroll
    for (int i = 0; i < 4; ++i) accO[i] = (frag_cd)(0.0f);
    float mst = -3.0e38f, lst = 0.f;   // per-lane state for q = qbase+fr (dup x4 quads)

    const int srow = t >> 2, scol = (t & 3) * 16;   // K/V staging
    const short* kg = (const short*)Kb + ((size_t)(b * KLEN + srow)) * E + h * DH + scol;
    const short* vg = (const short*)Vt + ((size_t)(b * E + h * DH + srow)) * KLEN + scol;
    const int ntb0 = 3 - w;            // wave BD window: n-tiles ntb0..ntb0+4
    const int b0 = 448 - q0;           // R band origin at kt=0 (0..448)
    const int qrow = qbase + fr;       // this lane's q

    // ---- initial R window: rows j = b0 .. b0+127 (always <= 575, no clamp) --
    {
        const int rr = t >> 1, rc = (t & 1) * 32;
        const int j = b0 + rr;
        const int slot = j & 127;
        const short* rp = (const short*)Rb + (size_t)j * E + h * DH + rc;
        *(uint4*)&Rs[slot][rc]      = *(const uint4*)(rp);
        *(uint4*)&Rs[slot][rc + 8]  = *(const uint4*)(rp + 8);
        *(uint4*)&Rs[slot][rc + 16] = *(const uint4*)(rp + 16);
        *(uint4*)&Rs[slot][rc + 24] = *(const uint4*)(rp + 24);
    }

    const int ntiles = 9 + qt;
    for (int kt = 0; kt < ntiles; ++kt) {
        const int k0 = kt * FK;
        __syncthreads();
        {   // stage K[64k][64d] and V^T[64d][64k]
            const short* kp = kg + (size_t)k0 * E;
            *(uint4*)&Ks[srow][scol]     = *(const uint4*)(kp);
            *(uint4*)&Ks[srow][scol + 8] = *(const uint4*)(kp + 8);
            const short* vp = vg + k0;
            *(uint4*)&Vs[srow][scol]     = *(const uint4*)(vp);
            *(uint4*)&Vs[srow][scol + 8] = *(const uint4*)(vp + 8);
        }
        if (kt >= 1) {   // slide R window: load 64 new rows
            const int r64 = t >> 2, rc = (t & 3) * 16;
            int j = b0 + 64 * kt + 64 + r64;
            const int slot = j & 127;
            if (j > KLEN - 1) j = KLEN - 1;   // clamped rows feed masked scores only
            const short* rp = (const short*)Rb + (size_t)j * E + h * DH + rc;
            *(uint4*)&Rs[slot][rc]     = *(const uint4*)(rp);
            *(uint4*)&Rs[slot][rc + 8] = *(const uint4*)(rp + 8);
        }
        __syncthreads();

        const int roff = (b0 + 64 * kt) & 127;   // band start slot

        // ---- BD^T tiles: D[j][q] = R·Qv^T; store [q][si], si = i*16+quad*4+r
        #pragma unroll
        for (int i = 0; i < 5; ++i) {
            const int ntb = ntb0 + i;
            const int slot = (roff + ntb * 16 + fr) & 127;
            const frag_ab rf0 = *(const frag_ab*)&Rs[slot][quad * 8];
            const frag_ab rf1 = *(const frag_ab*)&Rs[slot][32 + quad * 8];
            frag_cd z = (frag_cd)(0.0f);
            z = __builtin_amdgcn_mfma_f32_16x16x32_bf16(rf0, av0, z, 0, 0, 0);
            z = __builtin_amdgcn_mfma_f32_16x16x32_bf16(rf1, av1, z, 0, 0, 0);
            union { uint2 u; unsigned short sh[4]; } pk;
            pk.sh[0] = f2bs(z[0]); pk.sh[1] = f2bs(z[1]);
            pk.sh[2] = f2bs(z[2]); pk.sh[3] = f2bs(z[3]);
            *(uint2*)&BDs[w][fr][i * 16 + quad * 4] = pk.u;   // col q=fr, rows j
        }

        // ---- S^T = K·Qu^T: D[k][q] (col q = fr, row k = quad*4+r) ----
        frag_cd sc[4];
        #pragma unroll
        for (int nt = 0; nt < 4; ++nt) {
            const frag_ab kf0 = *(const frag_ab*)&Ks[nt * 16 + fr][quad * 8];
            const frag_ab kf1 = *(const frag_ab*)&Ks[nt * 16 + fr][32 + quad * 8];
            frag_cd z = (frag_cd)(0.0f);
            z = __builtin_amdgcn_mfma_f32_16x16x32_bf16(kf0, au0, z, 0, 0, 0);
            z = __builtin_amdgcn_mfma_f32_16x16x32_bf16(kf1, au1, z, 0, 0, 0);
            sc[nt] = z;
        }

        // ---- +BD, mask; all 16 values share q=qrow -> in-lane softmax ----
        float sv[4][4];
        float vmax = -3.0e38f;
        #pragma unroll
        for (int nt = 0; nt < 4; ++nt) {
            #pragma unroll
            for (int r = 0; r < 4; ++r) {
                const int kcol = k0 + nt * 16 + quad * 4 + r;
                const int si = nt * 16 + quad * 4 + r + 15 - fr;   // 0..78
                const float bd = bs2f(BDs[w][fr][si]);
                const float s = (sc[nt][r] + bd) * 0.125f;
                const float val = (kcol <= MEM + qrow) ? s : -1e30f;
                sv[nt][r] = val;
                vmax = fmaxf(vmax, val);
            }
        }
        vmax = fmaxf(vmax, __shfl_xor(vmax, 16, 64));
        vmax = fmaxf(vmax, __shfl_xor(vmax, 32, 64));
        const float mn = fmaxf(mst, vmax);
        float wsum = 0.f;
        unsigned short ph[4][4];
        #pragma unroll
        for (int nt = 0; nt < 4; ++nt) {
            #pragma unroll
            for (int r = 0; r < 4; ++r) {
                const float p = __expf(sv[nt][r] - mn);
                wsum += p;
                ph[nt][r] = f2bs(p);
            }
        }
        wsum += __shfl_xor(wsum, 16, 64);
        wsum += __shfl_xor(wsum, 32, 64);
        const float al = __expf(mst - mn);
        lst = lst * al + wsum;
        mst = mn;
        // alpha for accO regs (q on regs): fetch from lane holding that q
        float alr[4];
        #pragma unroll
        for (int r = 0; r < 4; ++r) alr[r] = __shfl(al, quad * 4 + r, 64);
        #pragma unroll
        for (int nt = 0; nt < 4; ++nt)
            #pragma unroll
            for (int r = 0; r < 4; ++r) accO[nt][r] *= alr[r];
        // P writes: row q=fr, k contiguous -> b64 per nt
        #pragma unroll
        for (int nt = 0; nt < 4; ++nt) {
            union { uint2 u; unsigned short sh[4]; } pk;
            pk.sh[0] = ph[nt][0]; pk.sh[1] = ph[nt][1];
            pk.sh[2] = ph[nt][2]; pk.sh[3] = ph[nt][3];
            *(uint2*)&Ps[w][fr][nt * 16 + quad * 4] = pk.u;
        }

        // ---- O += P·V (P as A-frag rows q; V^T as B-frag; same-wave LDS) ----
        const frag_ab pf0 = *(const frag_ab*)&Ps[w][fr][quad * 8];
        const frag_ab pf1 = *(const frag_ab*)&Ps[w][fr][32 + quad * 8];
        #pragma unroll
        for (int nt = 0; nt < 4; ++nt) {
            const frag_ab vf0 = *(const frag_ab*)&Vs[nt * 16 + fr][quad * 8];
            const frag_ab vf1 = *(const frag_ab*)&Vs[nt * 16 + fr][32 + quad * 8];
            accO[nt] = __builtin_amdgcn_mfma_f32_16x16x32_bf16(pf0, vf0, accO[nt], 0, 0, 0);
            accO[nt] = __builtin_amdgcn_mfma_f32_16x16x32_bf16(pf1, vf1, accO[nt], 0, 0, 0);
        }
    }

    const float linv = 1.0f / lst;
    #pragma unroll
    for (int r = 0; r < 4; ++r) {
        const float inv = __shfl(linv, quad * 4 + r, 64);
        bf16* po = O + ((size_t)(b * S + qbase + quad * 4 + r)) * E + h * DH + fr;
        #pragma unroll
        for (int nt = 0; nt < 4; ++nt)
            po[nt * 16] = __float2bfloat16(accO[nt][r] * inv);
    }
}

extern "C" void kernel_launch(void* const* d_in, const int* in_sizes, int n_in,
                              void* d_out, int out_size, void* d_ws, size_t ws_size,
                              hipStream_t stream)
{
    const float* obs  = (const float*)d_in[0];
    const float* mem  = (const float*)d_in[1];
    // d_in[2] = mask: deterministic (k <= MEM + q), recomputed in-kernel
    const float* Wenc = (const float*)d_in[3];
    const float* benc = (const float*)d_in[4];
    const float* ln1s = (const float*)d_in[5];
    const float* ln1b = (const float*)d_in[6];
    const float* Wq   = (const float*)d_in[7];
    const float* bq   = (const float*)d_in[8];
    const float* Wk   = (const float*)d_in[9];
    const float* bk   = (const float*)d_in[10];
    const float* Wv   = (const float*)d_in[11];
    const float* bv   = (const float*)d_in[12];
    const float* Wr   = (const float*)d_in[13];
    const float* ub   = (const float*)d_in[14];
    const float* vb   = (const float*)d_in[15];
    const float* Wo   = (const float*)d_in[16];
    const float* bo   = (const float*)d_in[17];
    const float* ln2s = (const float*)d_in[18];
    const float* ln2b = (const float*)d_in[19];
    const float* W1   = (const float*)d_in[20];
    const float* b1   = (const float*)d_in[21];
    const float* W2   = (const float*)d_in[22];
    const float* b2   = (const float*)d_in[23];

    // ---- workspace ----
    float* wsf = (float*)d_ws;
    float* X = wsf;                                   // fp32 [B*S*E]
    bf16* wsb = (bf16*)(wsf + (size_t)B * S * E);
    size_t ob = 0;
    bf16* OBSb = wsb + ob; ob += (size_t)B * S * OBS;
    bf16* QNb  = wsb + ob; ob += (size_t)B * S * E;
    bf16* PEb  = wsb + ob; ob += (size_t)KLEN * E;
    bf16* RBb  = wsb + ob; ob += (size_t)KLEN * E;
    bf16* WencT= wsb + ob; ob += (size_t)OBS * E;
    bf16* WqT  = wsb + ob; ob += (size_t)L * E * E;
    bf16* WkvT = wsb + ob; ob += (size_t)L * 2 * E * E;   // [L][1024][512]
    bf16* WrT  = wsb + ob; ob += (size_t)L * E * E;
    bf16* WoT  = wsb + ob; ob += (size_t)L * E * E;
    bf16* W1T  = wsb + ob; ob += (size_t)L * E * E;
    bf16* W2T  = wsb + ob; ob += (size_t)L * E * E;
    bf16* QUb  = wsb + ob; ob += (size_t)B * S * E;
    bf16* QVb  = wsb + ob; ob += (size_t)B * S * E;
    bf16* KBb  = wsb + ob; ob += (size_t)B * KLEN * E;
    bf16* VTb  = wsb + ob; ob += (size_t)B * E * KLEN;
    bf16* OBb  = wsb + ob; ob += (size_t)B * S * E;
    // union: {VKb, VBb} ∪ {HB, FFb} (disjoint lifetimes per layer)
    char* uni = (char*)(wsb + ob);
    bf16*  VKb = (bf16*)uni;                          // [B*KLEN][E] (8 MB) @0
    bf16*  VBb = (bf16*)(uni + ((size_t)8 << 20));    // [B*KLEN][E] (8 MB) @8M
    float* HB  = (float*)uni;                         // [B*S][E] fp32 (8 MB) @0
    bf16*  FFb = (bf16*)(uni + ((size_t)8 << 20));    // [B*S][E] (4 MB) @8M

    // ---- setup: merged weight transposes, obs cast + pe ----
    transpose_all_kernel<<<dim3(E / 32, E / 32, 29), 256, 0, stream>>>(
        Wq, Wk, Wv, Wr, Wo, W1, W2, Wenc, WqT, WkvT, WrT, WoT, W1T, W2T, WencT);
    setup_kernel<<<(B * S * OBS + KLEN * E) / 256, 256, 0, stream>>>(obs, OBSb, PEb);

    // encoder: X = obs @ W_enc + b_enc (fp32)
    mfma_gemm_kernel<<<dim3(E / 64, (B * S) / 128), 256, 0, stream>>>(
        OBSb, WencT, benc, nullptr, X, nullptr, OBS, E, 0);

    for (int li = 0; li < L; ++li) {
        const size_t wOff = (size_t)li * E * E;
        const size_t vOff = (size_t)li * E;

        ln1_kernel<<<2 * B * S, 256, 0, stream>>>(
            mem, X, li, ln1s + vOff, ln1b + vOff, QNb, VKb);

        qkvr_kernel<<<1344, 256, 0, stream>>>(
            QNb, VKb, PEb, WqT + wOff, WkvT + (size_t)li * 2 * E * E, WrT + wOff,
            bq + vOff, ub + vOff, vb + vOff, bk + vOff, bv + vOff,
            QUb, QVb, KBb, VBb, RBb);

        transpose_v_kernel<<<dim3(KLEN / 64, E / 64, B), 256, 0, stream>>>(VBb, VTb);

        mfma_flash_kernel<<<dim3(S / FQ, H, B), 256, 0, stream>>>(
            QUb, QVb, KBb, VTb, RBb, OBb);

        // HB = X + (O @ Wo + bo)
        mfma_gemm_kernel<<<dim3(E / 64, (B * S) / 128), 256, 0, stream>>>(
            OBb, WoT + wOff, bo + vOff, X, HB, nullptr, E, E, 0);
        ln_f32_kernel<<<B * S, 256, 0, stream>>>(HB, ln2s + vOff, ln2b + vOff, QNb);
        // FFb = gelu(hn @ W1 + b1)
        mfma_gemm_kernel<<<dim3(E / 64, (B * S) / 128), 256, 0, stream>>>(
            QNb, W1T + wOff, b1 + vOff, nullptr, nullptr, FFb, E, E, 1);
        // X = FF @ W2 + b2 + HB
        mfma_gemm_kernel<<<dim3(E / 64, (B * S) / 128), 256, 0, stream>>>(
            FFb, W2T + wOff, b2 + vOff, HB, X, nullptr, E, E, 0);
    }

    hipMemcpyAsync(d_out, X, (size_t)B * S * E * sizeof(float),
                   hipMemcpyDeviceToDevice, stream);
}